// Round 12
// baseline (85.410 us; speedup 1.0000x reference)
//
#include <hip/hip_runtime.h>

#define B_ 4
#define C_ 16
#define H_ 64
#define W_ 64
#define F_ 32
#define S_ 66                   // padded row stride
#define CH_ (S_ * S_)           // padded channel = 4356 floats
#define NPAD_ (B_ * C_ * CH_)   // 1.12 MB in d_ws
#define CST 12                  // LDS floats per (c,tap): n0..n5,d0..d3,pad2

// Prolog: physical zero-pad of x into d_ws as (B,C,66,66).
__global__ __launch_bounds__(256)
void pad_kernel(const float* __restrict__ x, float* __restrict__ xp) {
    const int i  = blockIdx.x * 256 + threadIdx.x;
    const int cc = i % S_;
    const int t  = i / S_;
    const int r  = t % S_;
    const int bc = t / S_;
    float v = 0.f;
    if (r >= 1 && r <= H_ && cc >= 1 && cc <= W_)
        v = x[(size_t)bc * (H_ * W_) + (r - 1) * W_ + (cc - 1)];
    xp[i] = v;
}

// 8 px/thread (full 8-row column) x 2 ch/thread (8-way channel split).
// Block 512 = 64 cols x 8 channel-groups, covers 8 rows x 64 cols of one (b,f).
// Grid 1024 = exactly 4 blocks/CU -> 32 waves/CU IF vgpr<=64.
// R10/R11 plateau theory: coeff DS reads still too dense per eval + live set
// over the 64-VGPR cliff. Here DS reads serve 72 evals each (27/ch, 2 ch) and
// live set ~58 VGPR (rv 30 + acc 8 + coeff 10 + addr).
__global__ __launch_bounds__(512)
void ka_rconv_kernel(const float* __restrict__ xp,
                     const float* __restrict__ nums,
                     const float* __restrict__ denoms,
                     float* __restrict__ out) {
    __shared__ alignas(16) float sc[C_ * 9 * CST];   // 6.9 KB coeffs for this f
    __shared__ float red[7 * 8 * 64];                // 14 KB partials (groups 1..7)

    const int tid = threadIdx.x;
    const int col = tid & 63;          // lane = column -> coalesced
    const int wg  = tid >> 6;          // channel group 0..7 (wave-uniform)

    int bid = blockIdx.x;
    const int f  = bid & 31;  bid >>= 5;
    const int t8 = bid & 7;   bid >>= 3;
    const int b  = bid;
    const int gy0 = t8 * 8;            // this block's 8 output rows

    // ---- stage this f's coefficients into LDS (coalesced, once per block) ----
    {
        const float* np = nums + (size_t)f * (C_ * 54);
        for (int i = tid; i < C_ * 54; i += 512) {
            int e = i / 6, j = i - e * 6;
            sc[e * CST + j] = np[i];
        }
        const float* dp = denoms + (size_t)f * (C_ * 36);
        for (int i = tid; i < C_ * 36; i += 512) {
            int e = i / 4, j = i - e * 4;
            sc[e * CST + 6 + j] = dp[i];
        }
    }
    __syncthreads();

    const int chb = __builtin_amdgcn_readfirstlane(wg * 2);
    const float* xb = xp + ((size_t)(b * C_ + chb)) * CH_ + gy0 * S_ + col;
    const float* cp = sc + chb * (9 * CST);

    float acc[8] = {0.f, 0.f, 0.f, 0.f, 0.f, 0.f, 0.f, 0.f};

    for (int c = 0; c < 2; ++c) {
        const float* xr = xb + c * CH_;
        float3 rv[10];                     // padded rows gy0..gy0+9, cols col..col+2
        #pragma unroll
        for (int k = 0; k < 10; ++k)
            rv[k] = *(const float3*)(xr + k * S_);   // global_load_dwordx3

        const float* ce = cp + c * (9 * CST);
        #pragma unroll
        for (int t = 0; t < 9; ++t) {
            const float4 k0 = *(const float4*)(ce + t * CST);      // n0 n1 n2 n3
            const float4 k1 = *(const float4*)(ce + t * CST + 4);  // n4 n5 d0 d1
            const float2 k2 = *(const float2*)(ce + t * CST + 8);  // d2 d3
            const int a = t / 3, j = t % 3;
            #pragma unroll
            for (int p = 0; p < 8; ++p) {
                const float3 r3 = rv[p + a];
                const float xv = (j == 0) ? r3.x : (j == 1) ? r3.y : r3.z;

                float P = fmaf(k1.y, xv, k1.x);
                P = fmaf(P, xv, k0.w);
                P = fmaf(P, xv, k0.z);
                P = fmaf(P, xv, k0.y);
                P = fmaf(P, xv, k0.x);

                float Q = fmaf(k2.y, xv, k2.x);
                Q = fmaf(Q, xv, k1.w);
                Q = fmaf(Q, xv, k1.z);
                Q *= xv;
                Q = 1.0f + fabsf(Q);

                acc[p] = fmaf(P, __builtin_amdgcn_rcpf(Q), acc[p]);
            }
        }
    }

    // 8-way channel reduction through LDS (wave-uniform branches).
    if (wg > 0) {
        #pragma unroll
        for (int p = 0; p < 8; ++p)
            red[((wg - 1) * 8 + p) * 64 + col] = acc[p];
    }
    __syncthreads();
    if (wg == 0) {
        float* op = out + (((size_t)b * F_ + f) * H_ + gy0) * W_ + col;
        #pragma unroll
        for (int p = 0; p < 8; ++p) {
            float s = acc[p];
            #pragma unroll
            for (int q = 0; q < 7; ++q)
                s += red[(q * 8 + p) * 64 + col];
            op[p * W_] = s;
        }
    }
}

extern "C" void kernel_launch(void* const* d_in, const int* in_sizes, int n_in,
                              void* d_out, int out_size, void* d_ws, size_t ws_size,
                              hipStream_t stream) {
    const float* x      = (const float*)d_in[0];
    const float* nums   = (const float*)d_in[1];
    const float* denoms = (const float*)d_in[2];
    float* outp = (float*)d_out;
    float* xpad = (float*)d_ws;

    pad_kernel<<<NPAD_ / 256, 256, 0, stream>>>(x, xpad);
    dim3 grid(B_ * 8 * F_);   // 1024 blocks: (b, 8-row tile, f)
    ka_rconv_kernel<<<grid, 512, 0, stream>>>(xpad, nums, denoms, outp);
}

// Round 13
// 80.965 us; speedup vs baseline: 1.0549x; 1.0549x over previous
//
#include <hip/hip_runtime.h>
#include <hip/hip_fp16.h>

#define B_ 4
#define C_ 16
#define H_ 64
#define W_ 64
#define F_ 32
#define S_ 66
#define CHW_ (S_ * S_)                 // padded plane = 4356
#define XN_ (B_ * 8 * CHW_)            // packed x entries (half2 ch-pairs) = 139392
#define CN_ (F_ * 8 * 9 * 12)          // packed coeff entries = 27648
#define CSTRIDE 12                     // half2 per (pair,tap): n0..n5,d0..d3,pad2

typedef _Float16 hvec2 __attribute__((ext_vector_type(2)));

// Prolog 1: pad + pack x as half2(channel c, channel c+8), layout [b][pr][66][66].
__global__ __launch_bounds__(256)
void pack_x_kernel(const float* __restrict__ x, __half2* __restrict__ xw) {
    const int i = blockIdx.x * 256 + threadIdx.x;
    if (i >= XN_) return;
    const int cc = i % S_;
    int t = i / S_;
    const int r  = t % S_;
    t /= S_;
    const int pr = t % 8;
    const int b  = t / 8;
    float lo = 0.f, hi = 0.f;
    if (r >= 1 && r <= H_ && cc >= 1 && cc <= W_) {
        const int sp = (r - 1) * W_ + (cc - 1);
        lo = x[((size_t)(b * C_ + pr)     ) * (H_ * W_) + sp];
        hi = x[((size_t)(b * C_ + pr + 8)) * (H_ * W_) + sp];
    }
    xw[i] = __halves2half2(__float2half_rn(lo), __float2half_rn(hi));
}

// Prolog 2: pack coefficients as half2(c=pr, c=pr+8), layout [f][pr][tap][12].
__global__ __launch_bounds__(256)
void pack_coef_kernel(const float* __restrict__ nums, const float* __restrict__ denoms,
                      __half2* __restrict__ cw) {
    const int i = blockIdx.x * 256 + threadIdx.x;   // one thread per (f,pr,tap)
    if (i >= F_ * 8 * 9) return;
    const int tap = i % 9;
    const int pr  = (i / 9) % 8;
    const int f   = i / 72;
    __half2* o = cw + (size_t)i * CSTRIDE;
    const size_t nlo = (((size_t)f * C_ + pr)     * 9 + tap) * 6;
    const size_t nhi = (((size_t)f * C_ + pr + 8) * 9 + tap) * 6;
    for (int k = 0; k < 6; ++k)
        o[k] = __halves2half2(__float2half_rn(nums[nlo + k]), __float2half_rn(nums[nhi + k]));
    const size_t dlo = (((size_t)f * C_ + pr)     * 9 + tap) * 4;
    const size_t dhi = (((size_t)f * C_ + pr + 8) * 9 + tap) * 4;
    for (int k = 0; k < 4; ++k)
        o[6 + k] = __halves2half2(__float2half_rn(denoms[dlo + k]), __float2half_rn(denoms[dhi + k]));
    o[10] = __halves2half2(__half(0.f), __half(0.f));
    o[11] = o[10];
}

// Main: 4 px/thread x 2 channel-pairs/thread, packed f16 eval (2 channels per
// instruction via v_pk_fma_f16 + v_dot2_f32_f16 accumulate).
// Block 256 = 64 cols x 4 wg; grid 2048 -> 8192 waves = 8/SIMD.
__global__ __launch_bounds__(256)
void ka_rconv_kernel(const __half2* __restrict__ xw,
                     const __half2* __restrict__ cw,
                     float* __restrict__ out) {
    __shared__ __half2 sc[8 * 9 * CSTRIDE];   // this f's packed coeffs, 3.4 KB
    __shared__ float red[3 * 4 * 64];

    const int tid = threadIdx.x;
    const int col = tid & 63;
    const int wg  = tid >> 6;          // 0..3 (wave-uniform)

    int bid = blockIdx.x;
    const int f  = bid & 31;  bid >>= 5;
    const int t4 = bid & 15;  bid >>= 4;
    const int b  = bid;
    const int gy0 = t4 * 4;

    // stage packed coeffs for this f (864 half2, coalesced)
    for (int i = tid; i < 8 * 9 * CSTRIDE; i += 256)
        sc[i] = cw[(size_t)f * (8 * 9 * CSTRIDE) + i];
    __syncthreads();

    const __half2 one = __halves2half2(__half(1.0f), __half(1.0f));
    float acc[4] = {0.f, 0.f, 0.f, 0.f};

    for (int cp = 0; cp < 2; ++cp) {
        const int pr = __builtin_amdgcn_readfirstlane(wg * 2 + cp);
        const __half2* xbase = xw + ((size_t)(b * 8 + pr) * S_ + gy0) * S_ + col;

        uint3 rv[6];    // 6 padded rows x 3 consecutive half2 (cols col..col+2)
        #pragma unroll
        for (int k = 0; k < 6; ++k)
            rv[k] = *(const uint3*)(xbase + k * S_);   // dwordx3

        const __half2* ce = sc + pr * (9 * CSTRIDE);
        #pragma unroll
        for (int t = 0; t < 9; ++t) {
            const __half2 n0 = ce[t*CSTRIDE+0], n1 = ce[t*CSTRIDE+1], n2 = ce[t*CSTRIDE+2];
            const __half2 n3 = ce[t*CSTRIDE+3], n4 = ce[t*CSTRIDE+4], n5 = ce[t*CSTRIDE+5];
            const __half2 d0 = ce[t*CSTRIDE+6], d1 = ce[t*CSTRIDE+7];
            const __half2 d2 = ce[t*CSTRIDE+8], d3 = ce[t*CSTRIDE+9];
            const int a = t / 3, j = t % 3;
            #pragma unroll
            for (int p = 0; p < 4; ++p) {
                const uint3 r3 = rv[p + a];
                const unsigned u = (j == 0) ? r3.x : (j == 1) ? r3.y : r3.z;
                const __half2 xp = __builtin_bit_cast(__half2, u);

                __half2 P = __hfma2(n5, xp, n4);
                P = __hfma2(P, xp, n3);
                P = __hfma2(P, xp, n2);
                P = __hfma2(P, xp, n1);
                P = __hfma2(P, xp, n0);

                __half2 Sd = __hfma2(d3, xp, d2);
                Sd = __hfma2(Sd, xp, d1);
                Sd = __hfma2(Sd, xp, d0);
                Sd = __hmul2(Sd, xp);

                const __half2 Q = __hadd2(one, __habs2(Sd));
                const __half2 R = h2rcp(Q);
#if __has_builtin(__builtin_amdgcn_fdot2)
                acc[p] = __builtin_amdgcn_fdot2(__builtin_bit_cast(hvec2, P),
                                                __builtin_bit_cast(hvec2, R),
                                                acc[p], false);
#else
                const __half2 PR = __hmul2(P, R);
                acc[p] += __low2float(PR) + __high2float(PR);
#endif
            }
        }
    }

    // 4-way reduction through LDS (wave-uniform branches).
    if (wg > 0) {
        #pragma unroll
        for (int p = 0; p < 4; ++p)
            red[((wg - 1) * 4 + p) * 64 + col] = acc[p];
    }
    __syncthreads();
    if (wg == 0) {
        float* op = out + (((size_t)b * F_ + f) * H_ + gy0) * W_ + col;
        #pragma unroll
        for (int p = 0; p < 4; ++p) {
            float s = acc[p] + red[(0 * 4 + p) * 64 + col]
                             + red[(1 * 4 + p) * 64 + col]
                             + red[(2 * 4 + p) * 64 + col];
            op[p * W_] = s;
        }
    }
}

extern "C" void kernel_launch(void* const* d_in, const int* in_sizes, int n_in,
                              void* d_out, int out_size, void* d_ws, size_t ws_size,
                              hipStream_t stream) {
    const float* x      = (const float*)d_in[0];
    const float* nums   = (const float*)d_in[1];
    const float* denoms = (const float*)d_in[2];
    float* outp = (float*)d_out;
    __half2* xw = (__half2*)d_ws;                    // XN_ entries
    __half2* cwp = xw + XN_;                         // CN_ entries; total ~668 KB

    pack_x_kernel<<<(XN_ + 255) / 256, 256, 0, stream>>>(x, xw);
    pack_coef_kernel<<<(F_ * 8 * 9 + 255) / 256, 256, 0, stream>>>(nums, denoms, cwp);
    dim3 grid(B_ * 16 * F_);   // 2048 blocks: (b, 4-row tile, f)
    ka_rconv_kernel<<<grid, 256, 0, stream>>>(xw, cwp, outp);
}

// Round 14
// 79.830 us; speedup vs baseline: 1.0699x; 1.0142x over previous
//
#include <hip/hip_runtime.h>
#include <hip/hip_fp16.h>

#define B_ 4
#define C_ 16
#define H_ 64
#define W_ 64
#define F_ 32
#define S_ 66
#define CHW_ (S_ * S_)                 // padded plane = 4356
#define XN_ (B_ * 8 * CHW_)            // packed x entries (half2 ch-pairs)
#define CPAIR 90                       // half2 per (f,pair): 9 taps x (6 nums + 4 denoms)
#define CN_ (F_ * 8 * CPAIR)

typedef _Float16 hvec2 __attribute__((ext_vector_type(2)));

// Prolog 1: pad + pack x as half2(channel c, channel c+8), layout [b][pr][66][66].
__global__ __launch_bounds__(256)
void pack_x_kernel(const float* __restrict__ x, __half2* __restrict__ xw) {
    const int i = blockIdx.x * 256 + threadIdx.x;
    if (i >= XN_) return;
    const int cc = i % S_;
    int t = i / S_;
    const int r  = t % S_;
    t /= S_;
    const int pr = t % 8;
    const int b  = t / 8;
    float lo = 0.f, hi = 0.f;
    if (r >= 1 && r <= H_ && cc >= 1 && cc <= W_) {
        const int sp = (r - 1) * W_ + (cc - 1);
        lo = x[((size_t)(b * C_ + pr)     ) * (H_ * W_) + sp];
        hi = x[((size_t)(b * C_ + pr + 8)) * (H_ * W_) + sp];
    }
    xw[i] = __halves2half2(__float2half_rn(lo), __float2half_rn(hi));
}

// Prolog 2: pack coeffs as half2(c=pr, c=pr+8), tight layout [f][pr][tap][10]
// (90 contiguous dwords per (f,pr) -> batched s_load in the main kernel).
__global__ __launch_bounds__(256)
void pack_coef_kernel(const float* __restrict__ nums, const float* __restrict__ denoms,
                      __half2* __restrict__ cw) {
    const int i = blockIdx.x * 256 + threadIdx.x;   // one thread per (f,pr,tap)
    if (i >= F_ * 8 * 9) return;
    const int tap = i % 9;
    const int pr  = (i / 9) % 8;
    const int f   = i / 72;
    __half2* o = cw + ((size_t)(f * 8 + pr) * 9 + tap) * 10;
    const size_t nlo = (((size_t)f * C_ + pr)     * 9 + tap) * 6;
    const size_t nhi = (((size_t)f * C_ + pr + 8) * 9 + tap) * 6;
    for (int k = 0; k < 6; ++k)
        o[k] = __halves2half2(__float2half_rn(nums[nlo + k]), __float2half_rn(nums[nhi + k]));
    const size_t dlo = (((size_t)f * C_ + pr)     * 9 + tap) * 4;
    const size_t dhi = (((size_t)f * C_ + pr + 8) * 9 + tap) * 4;
    for (int k = 0; k < 4; ++k)
        o[6 + k] = __halves2half2(__float2half_rn(denoms[dlo + k]), __float2half_rn(denoms[dhi + k]));
}

// Main: 4 px/thread x 2 ch-pairs/thread, f16 packed eval, coefficients from
// SGPRs (batched s_load, uniform base) -> ZERO LDS traffic in the hot loop.
// Block 256 = 64 cols x 4 wg; grid 2048 -> 8192 waves = 8/SIMD.
__global__ __launch_bounds__(256)
void ka_rconv_kernel(const __half2* __restrict__ xw,
                     const __half2* __restrict__ cw,
                     float* __restrict__ out) {
    __shared__ float red[3 * 4 * 64];

    const int tid = threadIdx.x;
    const int col = tid & 63;
    const int wg  = tid >> 6;          // 0..3 (wave-uniform)

    int bid = blockIdx.x;
    const int f  = bid & 31;  bid >>= 5;
    const int t4 = bid & 15;  bid >>= 4;
    const int b  = bid;
    const int gy0 = t4 * 4;

    const __half2 one = __halves2half2(__half(1.0f), __half(1.0f));
    float acc[4] = {0.f, 0.f, 0.f, 0.f};

    for (int cp = 0; cp < 2; ++cp) {
        const int pr = __builtin_amdgcn_readfirstlane(wg * 2 + cp);
        const __half2* xbase = xw + ((size_t)(b * 8 + pr) * S_ + gy0) * S_ + col;
        // uniform coeff base -> compiler emits batched s_load (R8-verified pattern)
        const __half2* ce = cw + (size_t)(f * 8 + pr) * CPAIR;

        uint3 rv[6];    // 6 padded rows x 3 consecutive half2 (cols col..col+2)
        #pragma unroll
        for (int k = 0; k < 6; ++k)
            rv[k] = *(const uint3*)(xbase + k * S_);   // dwordx3

        #pragma unroll
        for (int t = 0; t < 9; ++t) {
            const __half2 n0 = ce[t*10+0], n1 = ce[t*10+1], n2 = ce[t*10+2];
            const __half2 n3 = ce[t*10+3], n4 = ce[t*10+4], n5 = ce[t*10+5];
            const __half2 d0 = ce[t*10+6], d1 = ce[t*10+7];
            const __half2 d2 = ce[t*10+8], d3 = ce[t*10+9];
            const int a = t / 3, j = t % 3;
            #pragma unroll
            for (int p = 0; p < 4; ++p) {
                const uint3 r3 = rv[p + a];
                const unsigned u = (j == 0) ? r3.x : (j == 1) ? r3.y : r3.z;
                const __half2 xp = __builtin_bit_cast(__half2, u);

                __half2 P = __hfma2(n5, xp, n4);   // chain head: 1 v_mov per tap, amortized x4 px
                P = __hfma2(P, xp, n3);
                P = __hfma2(P, xp, n2);
                P = __hfma2(P, xp, n1);
                P = __hfma2(P, xp, n0);

                __half2 Sd = __hfma2(d3, xp, d2);
                Sd = __hfma2(Sd, xp, d1);
                Sd = __hfma2(Sd, xp, d0);
                Sd = __hmul2(Sd, xp);

                const __half2 Q = __hadd2(one, __habs2(Sd));
                const __half2 R = h2rcp(Q);
                acc[p] = __builtin_amdgcn_fdot2(__builtin_bit_cast(hvec2, P),
                                                __builtin_bit_cast(hvec2, R),
                                                acc[p], false);
            }
        }
    }

    // 4-way reduction through LDS (wave-uniform branches).
    if (wg > 0) {
        #pragma unroll
        for (int p = 0; p < 4; ++p)
            red[((wg - 1) * 4 + p) * 64 + col] = acc[p];
    }
    __syncthreads();
    if (wg == 0) {
        float* op = out + (((size_t)b * F_ + f) * H_ + gy0) * W_ + col;
        #pragma unroll
        for (int p = 0; p < 4; ++p) {
            float s = acc[p] + red[(0 * 4 + p) * 64 + col]
                             + red[(1 * 4 + p) * 64 + col]
                             + red[(2 * 4 + p) * 64 + col];
            op[p * W_] = s;
        }
    }
}

extern "C" void kernel_launch(void* const* d_in, const int* in_sizes, int n_in,
                              void* d_out, int out_size, void* d_ws, size_t ws_size,
                              hipStream_t stream) {
    const float* x      = (const float*)d_in[0];
    const float* nums   = (const float*)d_in[1];
    const float* denoms = (const float*)d_in[2];
    float* outp = (float*)d_out;
    __half2* xw = (__half2*)d_ws;                    // XN_ entries
    __half2* cwp = xw + XN_;                         // CN_ entries

    pack_x_kernel<<<(XN_ + 255) / 256, 256, 0, stream>>>(x, xw);
    pack_coef_kernel<<<(F_ * 8 * 9 + 255) / 256, 256, 0, stream>>>(nums, denoms, cwp);
    dim3 grid(B_ * 16 * F_);   // 2048 blocks: (b, 4-row tile, f)
    ka_rconv_kernel<<<grid, 256, 0, stream>>>(xw, cwp, outp);
}

// Round 15
// 78.643 us; speedup vs baseline: 1.0861x; 1.0151x over previous
//
#include <hip/hip_runtime.h>
#include <hip/hip_fp16.h>

#define B_ 4
#define C_ 16
#define H_ 64
#define W_ 64
#define F_ 32
#define S_ 66
#define CHW_ (S_ * S_)                 // padded plane = 4356
#define XN_ (B_ * 8 * CHW_)            // packed x entries (half2 ch-pairs) = 139392
#define CPAIR 90                       // half2 per (f,pair): 9 taps x (6 n + 4 d)
#define NC_ (F_ * 8 * 9)               // coeff pack work items = 2304

typedef _Float16 hvec2 __attribute__((ext_vector_type(2)));

// Single merged prolog: pads+packs x (half2 of channels c,c+8) AND packs
// coefficients, one launch. Work items [0,XN_) = x, [XN_, XN_+NC_) = coeffs.
__global__ __launch_bounds__(256)
void pack_kernel(const float* __restrict__ x,
                 const float* __restrict__ nums, const float* __restrict__ denoms,
                 __half2* __restrict__ xw, __half2* __restrict__ cw) {
    const int i = blockIdx.x * 256 + threadIdx.x;
    if (i < XN_) {
        const int cc = i % S_;
        int t = i / S_;
        const int r  = t % S_;
        t /= S_;
        const int pr = t % 8;
        const int b  = t / 8;
        float lo = 0.f, hi = 0.f;
        if (r >= 1 && r <= H_ && cc >= 1 && cc <= W_) {
            const int sp = (r - 1) * W_ + (cc - 1);
            lo = x[((size_t)(b * C_ + pr)     ) * (H_ * W_) + sp];
            hi = x[((size_t)(b * C_ + pr + 8)) * (H_ * W_) + sp];
        }
        xw[i] = __halves2half2(__float2half_rn(lo), __float2half_rn(hi));
    } else if (i < XN_ + NC_) {
        const int k = i - XN_;          // (f, pr, tap)
        const int tap = k % 9;
        const int pr  = (k / 9) % 8;
        const int f   = k / 72;
        __half2* o = cw + ((size_t)(f * 8 + pr) * 9 + tap) * 10;
        const size_t nlo = (((size_t)f * C_ + pr)     * 9 + tap) * 6;
        const size_t nhi = (((size_t)f * C_ + pr + 8) * 9 + tap) * 6;
        for (int q = 0; q < 6; ++q)
            o[q] = __halves2half2(__float2half_rn(nums[nlo + q]), __float2half_rn(nums[nhi + q]));
        const size_t dlo = (((size_t)f * C_ + pr)     * 9 + tap) * 4;
        const size_t dhi = (((size_t)f * C_ + pr + 8) * 9 + tap) * 4;
        for (int q = 0; q < 4; ++q)
            o[6 + q] = __halves2half2(__float2half_rn(denoms[dlo + q]), __float2half_rn(denoms[dhi + q]));
    }
}

// Main: 8 px/thread x EXACTLY 1 channel-pair/thread.
// Block 512 = 64 cols x 8 pair-groups, covers 8 rows x 64 cols of one (b,f).
// Grid 1024 -> 8192 waves = 8/SIMD. Coefficients: ONE batched s_load set per
// thread (90 dwords, uniform base) -- no second scalar-latency window.
__global__ __launch_bounds__(512)
void ka_rconv_kernel(const __half2* __restrict__ xw,
                     const __half2* __restrict__ cw,
                     float* __restrict__ out) {
    __shared__ float red[7 * 8 * 64];   // 14 KB partials (pair-groups 1..7)

    const int tid = threadIdx.x;
    const int col = tid & 63;
    const int wg  = tid >> 6;          // pair index 0..7 (wave-uniform)

    int bid = blockIdx.x;
    const int f  = bid & 31;  bid >>= 5;
    const int t8 = bid & 7;   bid >>= 3;
    const int b  = bid;
    const int gy0 = t8 * 8;

    const int pr = __builtin_amdgcn_readfirstlane(wg);
    const __half2* ce = cw + (size_t)(f * 8 + pr) * CPAIR;   // uniform -> s_load
    const __half2* xbase = xw + ((size_t)(b * 8 + pr) * S_ + gy0) * S_ + col;

    const __half2 one = __halves2half2(__half(1.0f), __half(1.0f));
    float acc[8] = {0.f, 0.f, 0.f, 0.f, 0.f, 0.f, 0.f, 0.f};

    uint3 rv[10];    // 10 padded rows x 3 consecutive half2 (cols col..col+2)
    #pragma unroll
    for (int k = 0; k < 10; ++k)
        rv[k] = *(const uint3*)(xbase + k * S_);   // global_load_dwordx3

    #pragma unroll
    for (int t = 0; t < 9; ++t) {
        const __half2 n0 = ce[t*10+0], n1 = ce[t*10+1], n2 = ce[t*10+2];
        const __half2 n3 = ce[t*10+3], n4 = ce[t*10+4], n5 = ce[t*10+5];
        const __half2 d0 = ce[t*10+6], d1 = ce[t*10+7];
        const __half2 d2 = ce[t*10+8], d3 = ce[t*10+9];
        const int a = t / 3, j = t % 3;
        #pragma unroll
        for (int p = 0; p < 8; ++p) {
            const uint3 r3 = rv[p + a];
            const unsigned u = (j == 0) ? r3.x : (j == 1) ? r3.y : r3.z;
            const __half2 xp = __builtin_bit_cast(__half2, u);

            __half2 P = __hfma2(n5, xp, n4);   // chain-head movs amortized over 8 px
            P = __hfma2(P, xp, n3);
            P = __hfma2(P, xp, n2);
            P = __hfma2(P, xp, n1);
            P = __hfma2(P, xp, n0);

            __half2 Sd = __hfma2(d3, xp, d2);
            Sd = __hfma2(Sd, xp, d1);
            Sd = __hfma2(Sd, xp, d0);
            Sd = __hmul2(Sd, xp);

            const __half2 Q = __hadd2(one, __habs2(Sd));
            const __half2 R = h2rcp(Q);
            acc[p] = __builtin_amdgcn_fdot2(__builtin_bit_cast(hvec2, P),
                                            __builtin_bit_cast(hvec2, R),
                                            acc[p], false);
        }
    }

    // 8-way pair reduction through LDS (wave-uniform branches).
    if (wg > 0) {
        #pragma unroll
        for (int p = 0; p < 8; ++p)
            red[((wg - 1) * 8 + p) * 64 + col] = acc[p];
    }
    __syncthreads();
    if (wg == 0) {
        float* op = out + (((size_t)b * F_ + f) * H_ + gy0) * W_ + col;
        #pragma unroll
        for (int p = 0; p < 8; ++p) {
            float s = acc[p];
            #pragma unroll
            for (int q = 0; q < 7; ++q)
                s += red[(q * 8 + p) * 64 + col];
            op[p * W_] = s;
        }
    }
}

extern "C" void kernel_launch(void* const* d_in, const int* in_sizes, int n_in,
                              void* d_out, int out_size, void* d_ws, size_t ws_size,
                              hipStream_t stream) {
    const float* x      = (const float*)d_in[0];
    const float* nums   = (const float*)d_in[1];
    const float* denoms = (const float*)d_in[2];
    float* outp = (float*)d_out;
    __half2* xw = (__half2*)d_ws;                    // XN_ entries
    __half2* cwp = xw + XN_;                         // F_*8*CPAIR entries

    pack_kernel<<<(XN_ + NC_ + 255) / 256, 256, 0, stream>>>(x, nums, denoms, xw, cwp);
    dim3 grid(B_ * 8 * F_);   // 1024 blocks: (b, 8-row tile, f)
    ka_rconv_kernel<<<grid, 512, 0, stream>>>(xw, cwp, outp);
}